// Round 17
// baseline (220.873 us; speedup 1.0000x reference)
//
#include <hip/hip_runtime.h>

typedef __attribute__((ext_vector_type(8))) __bf16 bf16x8;
typedef __attribute__((ext_vector_type(16))) float f32x16;

__device__ __forceinline__ unsigned short f2bf(float f) {
    unsigned int u = __float_as_uint(f);
    unsigned int r = (u + 0x7FFFu + ((u >> 16) & 1u)) >> 16;
    return (unsigned short)r;
}

// async global->LDS, 16B per lane (m97 pattern)
#define GLL16(gp, lp) \
    __builtin_amdgcn_global_load_lds( \
        (const __attribute__((address_space(1))) unsigned int*)(gp), \
        (__attribute__((address_space(3))) unsigned int*)(lp), 16, 0, 0)

// ---------------------------------------------------------------------------
// prep_all: fused prep (verified r15/r16).
//  gid <  349184:            w2 -> w2tf  [khpp 0..30][kw][s][lane][8], kh=khpp-4
//  349184 <= gid < 366080:   w1 -> w1t   [kw][oc][kh pad 48]
//  366080 <= gid < 417920:   zero h1s halo cols (11..15, 528..532)
// ---------------------------------------------------------------------------
__global__ __launch_bounds__(256) void prep_all(
    const float* __restrict__ w1, const float* __restrict__ w2,
    unsigned short* __restrict__ w1t, unsigned short* __restrict__ w2tf,
    unsigned short* __restrict__ h1s)
{
    const int gid = blockIdx.x * 256 + threadIdx.x;   // 1633 blocks
    if (gid < 349184) {
        const int j  = gid & 7;
        const int l  = (gid >> 3) & 63;
        const int s  = (gid >> 9) & 1;
        const int ti = gid >> 10;        // 0..340
        const int khpp = ti / 11;
        const int kw   = ti - khpp * 11;
        const int kh   = khpp - 4;
        const int oc   = l & 31;
        const int ic   = s * 16 + ((l >> 5) << 3) + j;
        unsigned short v = 0;
        if ((unsigned)kh <= 20u)
            v = f2bf(w2[((oc * 32 + ic) * 21 + kh) * 11 + kw]);
        w2tf[gid] = v;
    } else if (gid < 366080) {
        const int t = gid - 349184;      // 0..16895
        const int k    = t % 48;
        const int rest = t / 48;
        const int oc   = rest & 31;
        const int kw   = rest >> 5;
        unsigned short v = 0;
        if (k < 41) v = f2bf(w1[(oc * 41 + k) * 11 + kw]);
        w1t[t] = v;
    } else if (gid < 417920) {
        const int id = gid - 366080;     // 0..51839
        const int k  = id % 10;
        const int qq = (id / 10) & 3;
        const int nr = id / 40;          // 0..1295
        const int c  = (k < 5) ? 11 + k : 523 + k;   // 11..15, 528..532
        uint4 z = {0u, 0u, 0u, 0u};
        *(uint4*)((char*)h1s + ((size_t)(nr * 4 + qq) * 544 + c) * 16) = z;
    }
}

// ---------------------------------------------------------------------------
// conv1_mfma: conv1 (41x11, s(2,2), p(20,5)) + bias + bn1 + clip + mask,
// 11 kw-taps of M=32(oc) x K=48(kh zero-pad) x N=ow GEMM on mfma_32x32x16_bf16.
// Epilogue transposes through LDS into the planar 544-wide h1s layout.
// grid (4 ow-tiles, 41 oh-groups, 16 n), block 256.  (unchanged, verified)
// ---------------------------------------------------------------------------
__global__ __launch_bounds__(256) void conv1_mfma(
    const float* __restrict__ x, const int* __restrict__ xlen,
    const unsigned short* __restrict__ w1t,
    const float* __restrict__ b1, const float* __restrict__ g1,
    const float* __restrict__ be1, const float* __restrict__ m1,
    const float* __restrict__ v1,
    unsigned short* __restrict__ h1s)
{
    __shared__ uint4 lds4[2128];            // 34048 B: x-tile, then transpose buf
    char* lds = (char*)lds4;

    const int t  = threadIdx.x;
    const int bx = blockIdx.x;
    const int yi = blockIdx.y;
    const int n  = blockIdx.z;
    const int oh0 = ((yi >> 2) << 3) + (yi & 3);   // covers oh 0..80 with +4 pair
    const int len = xlen[n];

    const int l   = t & 63;
    const int w   = t >> 6;
    const int l31 = l & 31;
    const int lhi = l >> 5;

    char* h8 = (char*)h1s;
    const size_t rowpitch = 34816;          // 4 planes x 544 x 16B

    // dead strip: all cols masked -> store zeros, skip everything
    if (bx * 128 >= len) {
        #pragma unroll
        for (int it = 0; it < 4; ++it) {
            const int idx = t + it * 256;
            const int d1 = idx >> 9;
            const int q  = (idx >> 7) & 3;
            const int cl = idx & 127;
            const int oh = oh0 + 4 * d1;
            if (oh <= 80) {
                uint4 z = {0u, 0u, 0u, 0u};
                *(uint4*)(h8 + (size_t)(n * 81 + oh) * rowpitch + q * 8704
                          + (16 + (bx << 7) + cl) * 16) = z;
            }
        }
        return;
    }

    // ---- stage x: f32 -> bf16, transposed, swizzled ----
    const int cw   = t & 63;
    const int jrow = t >> 6;
    const int gr0  = 2 * oh0 - 20;
    const int gc0  = bx * 256 - 5;
    const float* xn = x + (size_t)n * 161 * 1024;
    #pragma unroll
    for (int cg = 0; cg < 5; ++cg) {
        const int c = cg * 64 + cw;
        if (c < 266) {
            const int gc = gc0 + c;
            const bool cok = (gc >= 0) && (gc < 1024);
            #pragma unroll
            for (int jj = 0; jj < 2; ++jj) {
                const int j = jrow + 4 * jj;       // chunk 0..6
                if (j < 7) {
                    unsigned int u[4];
                    #pragma unroll
                    for (int q = 0; q < 4; ++q) {
                        const int rA = gr0 + 8 * j + 2 * q;
                        float lo = 0.f, hi = 0.f;
                        if (cok && rA >= 0 && rA < 161)         lo = xn[(size_t)rA * 1024 + gc];
                        if (cok && rA + 1 >= 0 && rA + 1 < 161) hi = xn[(size_t)(rA + 1) * 1024 + gc];
                        u[q] = (unsigned int)f2bf(lo) | ((unsigned int)f2bf(hi) << 16);
                    }
                    uint4 val; val.x = u[0]; val.y = u[1]; val.z = u[2]; val.w = u[3];
                    *(uint4*)(lds + c * 128 + ((j ^ ((c >> 1) & 7)) << 4)) = val;
                }
            }
        }
    }
    __syncthreads();

    // ---- compute ----
    const int i = (w << 5) + l31;        // 0..127: ow within tile

    f32x16 acc0 = {}, acc1 = {};
    const char* w1tb = (const char*)w1t;
    #pragma unroll
    for (int kw = 0; kw < 11; ++kw) {
        const char* ap = w1tb + kw * 3072 + l31 * 96 + lhi * 16;
        const bf16x8 a0 = *(const bf16x8*)(ap);
        const bf16x8 a1 = *(const bf16x8*)(ap + 32);
        const bf16x8 a2 = *(const bf16x8*)(ap + 64);
        const int c = 2 * i + kw;
        const char* cb = lds + c * 128;
        const int sw = (c >> 1) & 7;
        const bf16x8 b00 = *(const bf16x8*)(cb + (((0 + lhi) ^ sw) << 4));
        const bf16x8 b01 = *(const bf16x8*)(cb + (((2 + lhi) ^ sw) << 4));
        const bf16x8 b02 = *(const bf16x8*)(cb + (((4 + lhi) ^ sw) << 4));
        const bf16x8 b10 = *(const bf16x8*)(cb + (((1 + lhi) ^ sw) << 4));
        const bf16x8 b11 = *(const bf16x8*)(cb + (((3 + lhi) ^ sw) << 4));
        const bf16x8 b12 = *(const bf16x8*)(cb + (((5 + lhi) ^ sw) << 4));
        acc0 = __builtin_amdgcn_mfma_f32_32x32x16_bf16(a0, b00, acc0, 0, 0, 0);
        acc0 = __builtin_amdgcn_mfma_f32_32x32x16_bf16(a1, b01, acc0, 0, 0, 0);
        acc0 = __builtin_amdgcn_mfma_f32_32x32x16_bf16(a2, b02, acc0, 0, 0, 0);
        acc1 = __builtin_amdgcn_mfma_f32_32x32x16_bf16(a0, b10, acc1, 0, 0, 0);
        acc1 = __builtin_amdgcn_mfma_f32_32x32x16_bf16(a1, b11, acc1, 0, 0, 0);
        acc1 = __builtin_amdgcn_mfma_f32_32x32x16_bf16(a2, b12, acc1, 0, 0, 0);
    }

    // ---- epilogue: bn1+clip+mask -> LDS transpose (planar) -> h1s ----
    __syncthreads();                     // x-tile reads done; reuse LDS
    const int ow  = bx * 128 + i;
    const bool vmask = ow < len;
    #pragma unroll
    for (int d1 = 0; d1 < 2; ++d1) {
        const int oh = oh0 + 4 * d1;
        if (oh <= 80) {
            #pragma unroll
            for (int q = 0; q < 4; ++q) {   // q = icq plane (oc>>3)
                float vv[4];
                #pragma unroll
                for (int rr = 0; rr < 4; ++rr) {
                    const int reg = (q << 2) + rr;
                    const int oc  = rr + (q << 3) + (lhi << 2);
                    const float s = g1[oc] * rsqrtf(v1[oc] + 1e-5f);
                    float val = ((d1 ? acc1[reg] : acc0[reg]) + b1[oc] - m1[oc]) * s + be1[oc];
                    val = fminf(fmaxf(val, 0.f), 20.f);
                    vv[rr] = vmask ? val : 0.f;
                }
                uint2 pk;
                pk.x = (unsigned int)f2bf(vv[0]) | ((unsigned int)f2bf(vv[1]) << 16);
                pk.y = (unsigned int)f2bf(vv[2]) | ((unsigned int)f2bf(vv[3]) << 16);
                *(uint2*)(lds + (((d1 << 2) + q) << 11) + i * 16 + lhi * 8) = pk;
            }
        }
    }
    __syncthreads();
    #pragma unroll
    for (int it = 0; it < 4; ++it) {
        const int idx = t + it * 256;    // 0..1023
        const int d1 = idx >> 9;
        const int q  = (idx >> 7) & 3;
        const int cl = idx & 127;
        const int oh = oh0 + 4 * d1;
        if (oh <= 80) {
            const uint4 v = *(const uint4*)(lds + (((d1 << 2) + q) << 11) + cl * 16);
            *(uint4*)(h8 + (size_t)(n * 81 + oh) * rowpitch + q * 8704
                      + (16 + (bx << 7) + cl) * 16) = v;
        }
    }
}

// ---------------------------------------------------------------------------
// conv2_v17: 3 INDEPENDENT v12-units packed into one 384-thread workgroup.
// Unit u (= tid>>7) runs v12's 2-wave barrier-free algorithm on its own
// 18432 B LDS slice; units share no data and have no in-loop barriers, so
// differing trip counts / dead states across units are safe. Forces >= 6
// waves/CU per resident workgroup (vs the ~3.4 hardware gave small blocks).
// Dead units skip the loop but keep the two epilogue __syncthreads.
// grid 896 = 2688 logical units / 3; XCD-affinity decode preserved:
// lb = (bid&7)*336 + (bid>>3)*3 + u  (each XCD owns n = {2k, 2k+1}).
// ---------------------------------------------------------------------------
__global__ __launch_bounds__(384, 2) void conv2_v17(
    const unsigned short* __restrict__ h1s, const unsigned short* __restrict__ w2tf,
    const int* __restrict__ xlen,
    const float* __restrict__ b2, const float* __restrict__ g2,
    const float* __restrict__ be2, const float* __restrict__ m2,
    const float* __restrict__ v2, float* __restrict__ out)
{
    __shared__ char ringall[3 * 18432];  // 55296 B = 3 unit-slices

    const int tid = threadIdx.x;
    const int u   = tid >> 7;            // unit 0..2
    const int t   = tid & 127;
    char* ring = ringall + u * 18432;

    const int w   = t >> 6;              // wave-in-unit = K-half s
    const int l   = t & 63;
    const int l31 = l & 31;
    const int lhi = l >> 5;

    // XCD-chunked bijective decode over 2688 logical units
    const int bid = blockIdx.x;          // 0..895
    const int lb  = (bid & 7) * 336 + (bid >> 3) * 3 + u;
    const int n   = lb / 168;
    const int rem = lb - n * 168;
    const int by  = rem >> 3;            // 0..20: oh2 pair {2by, 2by+1}
    const int bx  = rem & 7;

    const int ow0 = bx << 6;
    const int len = xlen[n];
    const int by4 = by << 2;

    const bool live = ow0 < len;

    f32x16 a00 = {}, a01 = {}, a10 = {}, a11 = {};   // [j][f]

    if (!live) {                         // fully masked col-tile: zeros only
        const int oh2 = 2 * by + w;
        if (oh2 <= 40) {
            #pragma unroll
            for (int f = 0; f < 2; ++f) {
                const int ow = ow0 + (f << 5) + l31;
                #pragma unroll
                for (int reg = 0; reg < 16; ++reg) {
                    const int oc = (reg & 3) + ((reg >> 2) << 3) + (lhi << 2);
                    out[((size_t)(n * 32 + oc) * 41 + oh2) * 512 + ow] = 0.f;
                }
            }
        }
    } else {
        const int rlo = (by4 - 10 > 0) ? by4 - 10 : 0;
        const int rhi = (by4 + 12 < 80) ? by4 + 12 : 80;

        const char* nb2 = (const char*)h1s + (size_t)(n * 81) * 34816;
        const char* w8v = (const char*)w2tf;

        // staging offsets: unit stages 4 planes x 96 cols x 16B = 6144 B/row,
        // 3 GLL16 issues per wave; wave w covers idx [w*192, w*192+192) ==
        // exactly the region it reads (disjoint across waves -> barrier-free).
        int gso[3], lso[3];
        #pragma unroll
        for (int i = 0; i < 3; ++i) {
            const int idx = w * 192 + i * 64 + l;    // 0..383
            const int q   = idx / 96;
            const int c   = idx - q * 96;
            gso[i] = q * 8704 + (ow0 + 11 + c) * 16;
            lso[i] = idx * 16;
        }

        #define STAGE(r, buf) do { \
            const char* g_ = nb2 + (size_t)(r) * 34816; \
            char* d_ = ring + (buf) * 6144; \
            GLL16(g_ + gso[0], d_ + lso[0]); \
            GLL16(g_ + gso[1], d_ + lso[1]); \
            GLL16(g_ + gso[2], d_ + lso[2]); \
        } while (0)

        #define LOADB(S, khppv) do { \
            _Pragma("unroll") \
            for (int kw = 0; kw < 11; ++kw) \
                S[kw] = *(const bf16x8*)(w8v \
                    + (size_t)((((khppv) * 11 + kw) * 2 + w) << 10) + (l << 4)); \
        } while (0)

        #define MFMAS(SJ0, TJ1, bufi) do { \
            const char* lb8_ = ring + (bufi) * 6144 + ((2 * w + lhi) * 96) * 16; \
            _Pragma("unroll") \
            for (int kw = 0; kw < 11; ++kw) { \
                const bf16x8 B0 = *(const bf16x8*)(lb8_ + (l31 + kw) * 16); \
                const bf16x8 B1 = *(const bf16x8*)(lb8_ + (l31 + kw + 32) * 16); \
                a00 = __builtin_amdgcn_mfma_f32_32x32x16_bf16(SJ0[kw], B0, a00, 0, 0, 0); \
                a01 = __builtin_amdgcn_mfma_f32_32x32x16_bf16(SJ0[kw], B1, a01, 0, 0, 0); \
                a10 = __builtin_amdgcn_mfma_f32_32x32x16_bf16(TJ1[kw], B0, a10, 0, 0, 0); \
                a11 = __builtin_amdgcn_mfma_f32_32x32x16_bf16(TJ1[kw], B1, a11, 0, 0, 0); \
            } \
        } while (0)

        // per-iter: A-loads for row r, stage row r+2, then fence so that only
        // STAGE(r+2) (3 ops) stays in flight -> A(r), STAGE(r), STAGE(r+1)
        // complete (in-order vmcnt); sched_barrier stops ds_read hoisting.
        #define ITER(kk, SC, SP, stbuf, rdbuf) do { \
            const int r_ = rlo + (kk); \
            LOADB(SC, r_ - by4 + 14); \
            { const int rs_ = (r_ + 2 <= rhi) ? (r_ + 2) : rhi; STAGE(rs_, stbuf); } \
            asm volatile("s_waitcnt vmcnt(3)" ::: "memory"); \
            __builtin_amdgcn_sched_barrier(0); \
            MFMAS(SC, SP, rdbuf); \
        } while (0)

        bf16x8 S0[11], S1[11], S2[11];
        // prologue: j1 window (burst(rlo-2) -> S1, burst(rlo-1) -> S2), rows 0,1
        LOADB(S1, rlo - by4 + 12);
        LOADB(S2, rlo - by4 + 13);
        STAGE(rlo,     0);
        STAGE(rlo + 1, 1);

        const int trips = rhi - rlo + 1;             // 11..23
        int k = 0;
        for (; k + 3 <= trips; k += 3) {
            ITER(k,     S0, S1, 2, 0);
            ITER(k + 1, S1, S2, 0, 1);
            ITER(k + 2, S2, S0, 1, 2);
        }
        // exact tail (k % 3 == 0 on exit; conditions uniform per unit)
        if (k < trips)     { ITER(k,     S0, S1, 2, 0); }
        if (k + 1 < trips) { ITER(k + 1, S1, S2, 0, 1); }
        #undef ITER
        #undef MFMAS
        #undef LOADB
        #undef STAGE
    }

    // ---- cross-wave s-reduction via LDS (16 KB in unit slice) ----
    __syncthreads();                     // full drain (vmcnt/lgkm) + sync
    if (live && w == 1) {
        #define WRPART(ACC, fi) do { \
            char* dst_ = ring + (fi) * 4096 + l * 64; \
            _Pragma("unroll") \
            for (int q = 0; q < 4; ++q) { \
                float4 v_; \
                v_.x = ACC[4*q]; v_.y = ACC[4*q+1]; v_.z = ACC[4*q+2]; v_.w = ACC[4*q+3]; \
                *(float4*)(dst_ + q * 16) = v_; \
            } \
        } while (0)
        WRPART(a00, 0); WRPART(a01, 1); WRPART(a10, 2); WRPART(a11, 3);
        #undef WRPART
    }
    __syncthreads();
    if (!live || w == 1) return;

    // ---- epilogue (live, wave 0): add partner acc, bn2 + clip + mask ----
    #define STOUT(ACC, fi, jv, fv) do { \
        const int oh2_ = 2 * by + (jv); \
        if (oh2_ <= 40) { \
            const char* src_ = ring + (fi) * 4096 + l * 64; \
            float pr_[16]; \
            _Pragma("unroll") \
            for (int q = 0; q < 4; ++q) { \
                const float4 v_ = *(const float4*)(src_ + q * 16); \
                pr_[4*q] = v_.x; pr_[4*q+1] = v_.y; pr_[4*q+2] = v_.z; pr_[4*q+3] = v_.w; \
            } \
            const int ow_ = ow0 + ((fv) << 5) + l31; \
            const bool valid_ = ow_ < len; \
            _Pragma("unroll") \
            for (int reg = 0; reg < 16; ++reg) { \
                const int oc_ = (reg & 3) + ((reg >> 2) << 3) + (lhi << 2); \
                const float sc_ = g2[oc_] * rsqrtf(v2[oc_] + 1e-5f); \
                float val_ = (ACC[reg] + pr_[reg] + b2[oc_] - m2[oc_]) * sc_ + be2[oc_]; \
                val_ = fminf(fmaxf(val_, 0.f), 20.f); \
                if (!valid_) val_ = 0.f; \
                out[((size_t)(n * 32 + oc_) * 41 + oh2_) * 512 + ow_] = val_; \
            } \
        } \
    } while (0)
    STOUT(a00, 0, 0, 0); STOUT(a01, 1, 0, 1); STOUT(a10, 2, 1, 0); STOUT(a11, 3, 1, 1);
    #undef STOUT
}

extern "C" void kernel_launch(void* const* d_in, const int* in_sizes, int n_in,
                              void* d_out, int out_size, void* d_ws, size_t ws_size,
                              hipStream_t stream) {
    const float* x    = (const float*)d_in[0];
    const int*   xlen = (const int*)  d_in[1];
    const float* w1   = (const float*)d_in[2];
    const float* b1   = (const float*)d_in[3];
    const float* g1   = (const float*)d_in[4];
    const float* be1  = (const float*)d_in[5];
    const float* m1   = (const float*)d_in[6];
    const float* v1   = (const float*)d_in[7];
    const float* w2   = (const float*)d_in[8];
    const float* b2   = (const float*)d_in[9];
    const float* g2   = (const float*)d_in[10];
    const float* be2  = (const float*)d_in[11];
    const float* m2   = (const float*)d_in[12];
    const float* v2   = (const float*)d_in[13];
    float* out = (float*)d_out;

    // ws: h1s planar 544-wide [22560768 sh], w2tf [349184 sh], w1t [16896 sh]
    unsigned short* h1s  = (unsigned short*)d_ws;
    unsigned short* w2tf = h1s + 22560768;
    unsigned short* w1t  = w2tf + 349184;

    prep_all<<<dim3(1633), dim3(256), 0, stream>>>(w1, w2, w1t, w2tf, h1s);
    conv1_mfma<<<dim3(4, 41, 16), dim3(256), 0, stream>>>(
        x, xlen, w1t, b1, g1, be1, m1, v1, h1s);
    conv2_v17<<<dim3(896), dim3(384), 0, stream>>>(
        h1s, w2tf, xlen, b2, g2, be2, m2, v2, out);
}

// Round 18
// 188.754 us; speedup vs baseline: 1.1702x; 1.1702x over previous
//
#include <hip/hip_runtime.h>

typedef __attribute__((ext_vector_type(8))) __bf16 bf16x8;
typedef __attribute__((ext_vector_type(16))) float f32x16;

__device__ __forceinline__ unsigned short f2bf(float f) {
    unsigned int u = __float_as_uint(f);
    unsigned int r = (u + 0x7FFFu + ((u >> 16) & 1u)) >> 16;
    return (unsigned short)r;
}

// async global->LDS, 16B per lane (m97 pattern)
#define GLL16(gp, lp) \
    __builtin_amdgcn_global_load_lds( \
        (const __attribute__((address_space(1))) unsigned int*)(gp), \
        (__attribute__((address_space(3))) unsigned int*)(lp), 16, 0, 0)

// ---------------------------------------------------------------------------
// prep_all: fused prep (verified r15/r16).
//  gid <  349184:            w2 -> w2tf  [khpp 0..30][kw][s][lane][8], kh=khpp-4
//  349184 <= gid < 366080:   w1 -> w1t   [kw][oc][kh pad 48]
//  366080 <= gid < 417920:   zero h1s halo cols (11..15, 528..532)
// ---------------------------------------------------------------------------
__global__ __launch_bounds__(256) void prep_all(
    const float* __restrict__ w1, const float* __restrict__ w2,
    unsigned short* __restrict__ w1t, unsigned short* __restrict__ w2tf,
    unsigned short* __restrict__ h1s)
{
    const int gid = blockIdx.x * 256 + threadIdx.x;   // 1633 blocks
    if (gid < 349184) {
        const int j  = gid & 7;
        const int l  = (gid >> 3) & 63;
        const int s  = (gid >> 9) & 1;
        const int ti = gid >> 10;        // 0..340
        const int khpp = ti / 11;
        const int kw   = ti - khpp * 11;
        const int kh   = khpp - 4;
        const int oc   = l & 31;
        const int ic   = s * 16 + ((l >> 5) << 3) + j;
        unsigned short v = 0;
        if ((unsigned)kh <= 20u)
            v = f2bf(w2[((oc * 32 + ic) * 21 + kh) * 11 + kw]);
        w2tf[gid] = v;
    } else if (gid < 366080) {
        const int t = gid - 349184;      // 0..16895
        const int k    = t % 48;
        const int rest = t / 48;
        const int oc   = rest & 31;
        const int kw   = rest >> 5;
        unsigned short v = 0;
        if (k < 41) v = f2bf(w1[(oc * 41 + k) * 11 + kw]);
        w1t[t] = v;
    } else if (gid < 417920) {
        const int id = gid - 366080;     // 0..51839
        const int k  = id % 10;
        const int qq = (id / 10) & 3;
        const int nr = id / 40;          // 0..1295
        const int c  = (k < 5) ? 11 + k : 523 + k;   // 11..15, 528..532
        uint4 z = {0u, 0u, 0u, 0u};
        *(uint4*)((char*)h1s + ((size_t)(nr * 4 + qq) * 544 + c) * 16) = z;
    }
}

// ---------------------------------------------------------------------------
// conv1_mfma: conv1 (41x11, s(2,2), p(20,5)) + bias + bn1 + clip + mask,
// 11 kw-taps of M=32(oc) x K=48(kh zero-pad) x N=ow GEMM on mfma_32x32x16_bf16.
// Epilogue transposes through LDS into the planar 544-wide h1s layout.
// grid (4 ow-tiles, 41 oh-groups, 16 n), block 256.  (unchanged, verified)
// ---------------------------------------------------------------------------
__global__ __launch_bounds__(256) void conv1_mfma(
    const float* __restrict__ x, const int* __restrict__ xlen,
    const unsigned short* __restrict__ w1t,
    const float* __restrict__ b1, const float* __restrict__ g1,
    const float* __restrict__ be1, const float* __restrict__ m1,
    const float* __restrict__ v1,
    unsigned short* __restrict__ h1s)
{
    __shared__ uint4 lds4[2128];            // 34048 B: x-tile, then transpose buf
    char* lds = (char*)lds4;

    const int t  = threadIdx.x;
    const int bx = blockIdx.x;
    const int yi = blockIdx.y;
    const int n  = blockIdx.z;
    const int oh0 = ((yi >> 2) << 3) + (yi & 3);   // covers oh 0..80 with +4 pair
    const int len = xlen[n];

    const int l   = t & 63;
    const int w   = t >> 6;
    const int l31 = l & 31;
    const int lhi = l >> 5;

    char* h8 = (char*)h1s;
    const size_t rowpitch = 34816;          // 4 planes x 544 x 16B

    // dead strip: all cols masked -> store zeros, skip everything
    if (bx * 128 >= len) {
        #pragma unroll
        for (int it = 0; it < 4; ++it) {
            const int idx = t + it * 256;
            const int d1 = idx >> 9;
            const int q  = (idx >> 7) & 3;
            const int cl = idx & 127;
            const int oh = oh0 + 4 * d1;
            if (oh <= 80) {
                uint4 z = {0u, 0u, 0u, 0u};
                *(uint4*)(h8 + (size_t)(n * 81 + oh) * rowpitch + q * 8704
                          + (16 + (bx << 7) + cl) * 16) = z;
            }
        }
        return;
    }

    // ---- stage x: f32 -> bf16, transposed, swizzled ----
    const int cw   = t & 63;
    const int jrow = t >> 6;
    const int gr0  = 2 * oh0 - 20;
    const int gc0  = bx * 256 - 5;
    const float* xn = x + (size_t)n * 161 * 1024;
    #pragma unroll
    for (int cg = 0; cg < 5; ++cg) {
        const int c = cg * 64 + cw;
        if (c < 266) {
            const int gc = gc0 + c;
            const bool cok = (gc >= 0) && (gc < 1024);
            #pragma unroll
            for (int jj = 0; jj < 2; ++jj) {
                const int j = jrow + 4 * jj;       // chunk 0..6
                if (j < 7) {
                    unsigned int u[4];
                    #pragma unroll
                    for (int q = 0; q < 4; ++q) {
                        const int rA = gr0 + 8 * j + 2 * q;
                        float lo = 0.f, hi = 0.f;
                        if (cok && rA >= 0 && rA < 161)         lo = xn[(size_t)rA * 1024 + gc];
                        if (cok && rA + 1 >= 0 && rA + 1 < 161) hi = xn[(size_t)(rA + 1) * 1024 + gc];
                        u[q] = (unsigned int)f2bf(lo) | ((unsigned int)f2bf(hi) << 16);
                    }
                    uint4 val; val.x = u[0]; val.y = u[1]; val.z = u[2]; val.w = u[3];
                    *(uint4*)(lds + c * 128 + ((j ^ ((c >> 1) & 7)) << 4)) = val;
                }
            }
        }
    }
    __syncthreads();

    // ---- compute ----
    const int i = (w << 5) + l31;        // 0..127: ow within tile

    f32x16 acc0 = {}, acc1 = {};
    const char* w1tb = (const char*)w1t;
    #pragma unroll
    for (int kw = 0; kw < 11; ++kw) {
        const char* ap = w1tb + kw * 3072 + l31 * 96 + lhi * 16;
        const bf16x8 a0 = *(const bf16x8*)(ap);
        const bf16x8 a1 = *(const bf16x8*)(ap + 32);
        const bf16x8 a2 = *(const bf16x8*)(ap + 64);
        const int c = 2 * i + kw;
        const char* cb = lds + c * 128;
        const int sw = (c >> 1) & 7;
        const bf16x8 b00 = *(const bf16x8*)(cb + (((0 + lhi) ^ sw) << 4));
        const bf16x8 b01 = *(const bf16x8*)(cb + (((2 + lhi) ^ sw) << 4));
        const bf16x8 b02 = *(const bf16x8*)(cb + (((4 + lhi) ^ sw) << 4));
        const bf16x8 b10 = *(const bf16x8*)(cb + (((1 + lhi) ^ sw) << 4));
        const bf16x8 b11 = *(const bf16x8*)(cb + (((3 + lhi) ^ sw) << 4));
        const bf16x8 b12 = *(const bf16x8*)(cb + (((5 + lhi) ^ sw) << 4));
        acc0 = __builtin_amdgcn_mfma_f32_32x32x16_bf16(a0, b00, acc0, 0, 0, 0);
        acc0 = __builtin_amdgcn_mfma_f32_32x32x16_bf16(a1, b01, acc0, 0, 0, 0);
        acc0 = __builtin_amdgcn_mfma_f32_32x32x16_bf16(a2, b02, acc0, 0, 0, 0);
        acc1 = __builtin_amdgcn_mfma_f32_32x32x16_bf16(a0, b10, acc1, 0, 0, 0);
        acc1 = __builtin_amdgcn_mfma_f32_32x32x16_bf16(a1, b11, acc1, 0, 0, 0);
        acc1 = __builtin_amdgcn_mfma_f32_32x32x16_bf16(a2, b12, acc1, 0, 0, 0);
    }

    // ---- epilogue: bn1+clip+mask -> LDS transpose (planar) -> h1s ----
    __syncthreads();                     // x-tile reads done; reuse LDS
    const int ow  = bx * 128 + i;
    const bool vmask = ow < len;
    #pragma unroll
    for (int d1 = 0; d1 < 2; ++d1) {
        const int oh = oh0 + 4 * d1;
        if (oh <= 80) {
            #pragma unroll
            for (int q = 0; q < 4; ++q) {   // q = icq plane (oc>>3)
                float vv[4];
                #pragma unroll
                for (int rr = 0; rr < 4; ++rr) {
                    const int reg = (q << 2) + rr;
                    const int oc  = rr + (q << 3) + (lhi << 2);
                    const float s = g1[oc] * rsqrtf(v1[oc] + 1e-5f);
                    float val = ((d1 ? acc1[reg] : acc0[reg]) + b1[oc] - m1[oc]) * s + be1[oc];
                    val = fminf(fmaxf(val, 0.f), 20.f);
                    vv[rr] = vmask ? val : 0.f;
                }
                uint2 pk;
                pk.x = (unsigned int)f2bf(vv[0]) | ((unsigned int)f2bf(vv[1]) << 16);
                pk.y = (unsigned int)f2bf(vv[2]) | ((unsigned int)f2bf(vv[3]) << 16);
                *(uint2*)(lds + (((d1 << 2) + q) << 11) + i * 16 + lhi * 8) = pk;
            }
        }
    }
    __syncthreads();
    #pragma unroll
    for (int it = 0; it < 4; ++it) {
        const int idx = t + it * 256;    // 0..1023
        const int d1 = idx >> 9;
        const int q  = (idx >> 7) & 3;
        const int cl = idx & 127;
        const int oh = oh0 + 4 * d1;
        if (oh <= 80) {
            const uint4 v = *(const uint4*)(lds + (((d1 << 2) + q) << 11) + cl * 16);
            *(uint4*)(h8 + (size_t)(n * 81 + oh) * rowpitch + q * 8704
                      + (16 + (bx << 7) + cl) * 16) = v;
        }
    }
}

// ---------------------------------------------------------------------------
// conv2_v12 (verbatim best-verified: conv2 ~144 us):
// XCD-n-affinity decode, barrier-free 2-wave blocks (disjoint LDS regions),
// ring-3 LDS, 3-slot A rotation, single vmcnt(3)+sched_barrier fence/iter.
// ---------------------------------------------------------------------------
__global__ __launch_bounds__(128, 2) void conv2_v12(
    const unsigned short* __restrict__ h1s, const unsigned short* __restrict__ w2tf,
    const int* __restrict__ xlen,
    const float* __restrict__ b2, const float* __restrict__ g2,
    const float* __restrict__ be2, const float* __restrict__ m2,
    const float* __restrict__ v2, float* __restrict__ out)
{
    __shared__ char ring[3 * 6144];      // 18432 B

    const int t   = threadIdx.x;
    const int w   = t >> 6;              // wave = K-half s
    const int l   = t & 63;
    const int l31 = l & 31;
    const int lhi = l >> 5;

    // XCD-chunked bijective decode: 2688 = 8 x 336; XCD k owns n = {2k, 2k+1}
    const int bid = blockIdx.x;
    const int lb  = (bid & 7) * 336 + (bid >> 3);
    const int n   = lb / 168;
    const int rem = lb - n * 168;
    const int by  = rem >> 3;            // 0..20: oh2 pair {2by, 2by+1}
    const int bx  = rem & 7;

    const int ow0 = bx << 6;
    const int len = xlen[n];
    const int by4 = by << 2;

    if (ow0 >= len) {                    // fully masked col-tile: zeros only
        const int oh2 = 2 * by + w;
        if (oh2 <= 40) {
            #pragma unroll
            for (int f = 0; f < 2; ++f) {
                const int ow = ow0 + (f << 5) + l31;
                #pragma unroll
                for (int reg = 0; reg < 16; ++reg) {
                    const int oc = (reg & 3) + ((reg >> 2) << 3) + (lhi << 2);
                    out[((size_t)(n * 32 + oc) * 41 + oh2) * 512 + ow] = 0.f;
                }
            }
        }
        return;
    }

    const int rlo = (by4 - 10 > 0) ? by4 - 10 : 0;
    const int rhi = (by4 + 12 < 80) ? by4 + 12 : 80;

    f32x16 a00 = {}, a01 = {}, a10 = {}, a11 = {};   // [j][f]

    const char* nb2 = (const char*)h1s + (size_t)(n * 81) * 34816;
    const char* w8v = (const char*)w2tf;

    // staging offsets: block stages 4 planes x 96 cols x 16B = 6144 B/row,
    // 3 GLL16 issues per wave; wave w covers idx [w*192, w*192+192) == exactly
    // the region it reads (disjoint across waves -> barrier-free).
    int gso[3], lso[3];
    #pragma unroll
    for (int i = 0; i < 3; ++i) {
        const int idx = w * 192 + i * 64 + l;        // 0..383
        const int q   = idx / 96;
        const int c   = idx - q * 96;
        gso[i] = q * 8704 + (ow0 + 11 + c) * 16;
        lso[i] = idx * 16;
    }

    #define STAGE(r, buf) do { \
        const char* g_ = nb2 + (size_t)(r) * 34816; \
        char* d_ = ring + (buf) * 6144; \
        GLL16(g_ + gso[0], d_ + lso[0]); \
        GLL16(g_ + gso[1], d_ + lso[1]); \
        GLL16(g_ + gso[2], d_ + lso[2]); \
    } while (0)

    #define LOADB(S, khppv) do { \
        _Pragma("unroll") \
        for (int kw = 0; kw < 11; ++kw) \
            S[kw] = *(const bf16x8*)(w8v \
                + (size_t)((((khppv) * 11 + kw) * 2 + w) << 10) + (l << 4)); \
    } while (0)

    #define MFMAS(SJ0, TJ1, bufi) do { \
        const char* lb8_ = ring + (bufi) * 6144 + ((2 * w + lhi) * 96) * 16; \
        _Pragma("unroll") \
        for (int kw = 0; kw < 11; ++kw) { \
            const bf16x8 B0 = *(const bf16x8*)(lb8_ + (l31 + kw) * 16); \
            const bf16x8 B1 = *(const bf16x8*)(lb8_ + (l31 + kw + 32) * 16); \
            a00 = __builtin_amdgcn_mfma_f32_32x32x16_bf16(SJ0[kw], B0, a00, 0, 0, 0); \
            a01 = __builtin_amdgcn_mfma_f32_32x32x16_bf16(SJ0[kw], B1, a01, 0, 0, 0); \
            a10 = __builtin_amdgcn_mfma_f32_32x32x16_bf16(TJ1[kw], B0, a10, 0, 0, 0); \
            a11 = __builtin_amdgcn_mfma_f32_32x32x16_bf16(TJ1[kw], B1, a11, 0, 0, 0); \
        } \
    } while (0)

    // per-iter: A-loads for row r, stage row r+2, then fence so that
    // only STAGE(r+2) (3 ops) stays in flight -> A(r), STAGE(r), STAGE(r+1)
    // are complete (in-order vmcnt); sched_barrier stops ds_read hoisting.
    #define ITER(kk, SC, SP, stbuf, rdbuf) do { \
        const int r_ = rlo + (kk); \
        LOADB(SC, r_ - by4 + 14); \
        { const int rs_ = (r_ + 2 <= rhi) ? (r_ + 2) : rhi; STAGE(rs_, stbuf); } \
        asm volatile("s_waitcnt vmcnt(3)" ::: "memory"); \
        __builtin_amdgcn_sched_barrier(0); \
        MFMAS(SC, SP, rdbuf); \
    } while (0)

    bf16x8 S0[11], S1[11], S2[11];
    // prologue: j1 window (burst(rlo-2) -> S1, burst(rlo-1) -> S2), rows 0,1
    LOADB(S1, rlo - by4 + 12);
    LOADB(S2, rlo - by4 + 13);
    STAGE(rlo,     0);
    STAGE(rlo + 1, 1);

    const int trips = rhi - rlo + 1;                 // 11..23
    int k = 0;
    for (; k + 3 <= trips; k += 3) {
        ITER(k,     S0, S1, 2, 0);
        ITER(k + 1, S1, S2, 0, 1);
        ITER(k + 2, S2, S0, 1, 2);
    }
    // exact tail (k % 3 == 0 on exit; conditions uniform per block)
    if (k < trips)     { ITER(k,     S0, S1, 2, 0); }
    if (k + 1 < trips) { ITER(k + 1, S1, S2, 0, 1); }
    #undef ITER
    #undef MFMAS
    #undef LOADB
    #undef STAGE

    // ---- cross-wave s-reduction via LDS (16 KB in ring) ----
    __syncthreads();                     // full drain (vmcnt/lgkm) + sync
    if (w == 1) {
        #define WRPART(ACC, fi) do { \
            char* dst_ = ring + (fi) * 4096 + l * 64; \
            _Pragma("unroll") \
            for (int q = 0; q < 4; ++q) { \
                float4 v_; \
                v_.x = ACC[4*q]; v_.y = ACC[4*q+1]; v_.z = ACC[4*q+2]; v_.w = ACC[4*q+3]; \
                *(float4*)(dst_ + q * 16) = v_; \
            } \
        } while (0)
        WRPART(a00, 0); WRPART(a01, 1); WRPART(a10, 2); WRPART(a11, 3);
        #undef WRPART
    }
    __syncthreads();
    if (w == 1) return;

    // ---- epilogue (wave 0): add partner acc, bn2 + clip + mask -> out ----
    #define STOUT(ACC, fi, jv, fv) do { \
        const int oh2_ = 2 * by + (jv); \
        if (oh2_ <= 40) { \
            const char* src_ = ring + (fi) * 4096 + l * 64; \
            float pr_[16]; \
            _Pragma("unroll") \
            for (int q = 0; q < 4; ++q) { \
                const float4 v_ = *(const float4*)(src_ + q * 16); \
                pr_[4*q] = v_.x; pr_[4*q+1] = v_.y; pr_[4*q+2] = v_.z; pr_[4*q+3] = v_.w; \
            } \
            const int ow_ = ow0 + ((fv) << 5) + l31; \
            const bool valid_ = ow_ < len; \
            _Pragma("unroll") \
            for (int reg = 0; reg < 16; ++reg) { \
                const int oc_ = (reg & 3) + ((reg >> 2) << 3) + (lhi << 2); \
                const float sc_ = g2[oc_] * rsqrtf(v2[oc_] + 1e-5f); \
                float val_ = (ACC[reg] + pr_[reg] + b2[oc_] - m2[oc_]) * sc_ + be2[oc_]; \
                val_ = fminf(fmaxf(val_, 0.f), 20.f); \
                if (!valid_) val_ = 0.f; \
                out[((size_t)(n * 32 + oc_) * 41 + oh2_) * 512 + ow_] = val_; \
            } \
        } \
    } while (0)
    STOUT(a00, 0, 0, 0); STOUT(a01, 1, 0, 1); STOUT(a10, 2, 1, 0); STOUT(a11, 3, 1, 1);
    #undef STOUT
}

extern "C" void kernel_launch(void* const* d_in, const int* in_sizes, int n_in,
                              void* d_out, int out_size, void* d_ws, size_t ws_size,
                              hipStream_t stream) {
    const float* x    = (const float*)d_in[0];
    const int*   xlen = (const int*)  d_in[1];
    const float* w1   = (const float*)d_in[2];
    const float* b1   = (const float*)d_in[3];
    const float* g1   = (const float*)d_in[4];
    const float* be1  = (const float*)d_in[5];
    const float* m1   = (const float*)d_in[6];
    const float* v1   = (const float*)d_in[7];
    const float* w2   = (const float*)d_in[8];
    const float* b2   = (const float*)d_in[9];
    const float* g2   = (const float*)d_in[10];
    const float* be2  = (const float*)d_in[11];
    const float* m2   = (const float*)d_in[12];
    const float* v2   = (const float*)d_in[13];
    float* out = (float*)d_out;

    // ws: h1s planar 544-wide [22560768 sh], w2tf [349184 sh], w1t [16896 sh]
    unsigned short* h1s  = (unsigned short*)d_ws;
    unsigned short* w2tf = h1s + 22560768;
    unsigned short* w1t  = w2tf + 349184;

    prep_all<<<dim3(1633), dim3(256), 0, stream>>>(w1, w2, w1t, w2tf, h1s);
    conv1_mfma<<<dim3(4, 41, 16), dim3(256), 0, stream>>>(
        x, xlen, w1t, b1, g1, be1, m1, v1, h1s);
    conv2_v12<<<dim3(2688), dim3(128), 0, stream>>>(
        h1s, w2tf, xlen, b2, g2, be2, m2, v2, out);
}